// Round 1
// baseline (723.868 us; speedup 1.0000x reference)
//
#include <hip/hip_runtime.h>

// toy_gnn scatter-add: out[dst[e], f] += w_mp * edge_weight[e] * x[src[e], f]
// N=100000 nodes, E=1600000 edges, F=32 features, all fp32.
// Round 0: straightforward device-atomic scatter, 8 threads/edge (float4 each).

constexpr int N_NODES = 100000;
constexpr int N_EDGES = 1600000;
constexpr int F_DIM   = 32;

__global__ __launch_bounds__(256) void gnn_scatter_atomic(
    const float* __restrict__ x,        // [N, F]
    const int*   __restrict__ src,      // [E]
    const int*   __restrict__ dst,      // [E]
    const float* __restrict__ ew,       // [E]
    const float* __restrict__ w_mp,     // [1]
    float*       __restrict__ out)      // [N, F]
{
    const float w = w_mp[0];
    int gid = blockIdx.x * blockDim.x + threadIdx.x;
    int e = gid >> 3;           // 8 threads per edge
    int q = (gid & 7) * 4;      // float4 chunk within the 32-float row
    if (e >= N_EDGES) return;

    int s = src[e];
    int d = dst[e];
    float c = w * ew[e];

    const float4 xv = *reinterpret_cast<const float4*>(x + (long long)s * F_DIM + q);
    float* op = out + (long long)d * F_DIM + q;
    atomicAdd(op + 0, c * xv.x);
    atomicAdd(op + 1, c * xv.y);
    atomicAdd(op + 2, c * xv.z);
    atomicAdd(op + 3, c * xv.w);
}

extern "C" void kernel_launch(void* const* d_in, const int* in_sizes, int n_in,
                              void* d_out, int out_size, void* d_ws, size_t ws_size,
                              hipStream_t stream) {
    const float* x    = (const float*)d_in[0];
    const int*   ei   = (const int*)d_in[1];      // [2, E] row-major: src then dst
    const float* ew   = (const float*)d_in[2];
    const float* w_mp = (const float*)d_in[3];
    float* out = (float*)d_out;

    const int* src = ei;
    const int* dst = ei + N_EDGES;

    // d_out is poisoned with 0xAA before every timed launch — zero it first.
    hipMemsetAsync(d_out, 0, (size_t)out_size * sizeof(float), stream);

    int total_threads = N_EDGES * 8;
    int block = 256;
    int grid = (total_threads + block - 1) / block;
    gnn_scatter_atomic<<<grid, block, 0, stream>>>(x, src, dst, ew, w_mp, out);
}

// Round 2
// 295.438 us; speedup vs baseline: 2.4502x; 2.4502x over previous
//
#include <hip/hip_runtime.h>

// toy_gnn scatter-add: out[dst[e], f] += w_mp * edge_weight[e] * x[src[e], f]
// N=100000, E=1600000, F=32, fp32.
//
// Round 1: CSR counting-sort + atomic-free segmented sum.
//   R0 profile: 819 MB HBM WRITE_SIZE (= 51.2M atomics x 16B write-through),
//   VALUBusy 1.2% -> pure atomic-throughput bound. Replace fp32 atomic scatter
//   with: deg histogram (1.6M int atomics) -> scan -> scatter packed (src,coef)
//   pairs grouped by dst (1.6M int atomics) -> per-node gather-sum (0 atomics,
//   one coalesced float4 store per 8-thread group).

constexpr int N_NODES = 100000;
constexpr int N_EDGES = 1600000;
constexpr int F_DIM   = 32;
constexpr int BLOCK   = 256;
constexpr int N_SCAN_BLOCKS = (N_NODES + BLOCK - 1) / BLOCK;  // 391

// ---------------- workspace layout (bytes) ----------------
constexpr size_t WS_DEG     = 0;                          // N ints
constexpr size_t WS_OFFS    = 400000;                     // N+1 ints
constexpr size_t WS_CURSOR  = 800016;                     // N ints
constexpr size_t WS_BSUMS   = 1200016;                    // 391 ints
constexpr size_t WS_PAIRS   = 1201600;                    // E int2 (src, coef-bits)
constexpr size_t WS_NEEDED  = WS_PAIRS + (size_t)N_EDGES * 8;  // ~14.0 MB

__global__ __launch_bounds__(BLOCK) void hist_deg(
    const int* __restrict__ dst, int* __restrict__ deg)
{
    int e = blockIdx.x * BLOCK + threadIdx.x;
    if (e < N_EDGES) atomicAdd(&deg[dst[e]], 1);
}

__global__ __launch_bounds__(BLOCK) void block_reduce_deg(
    const int* __restrict__ deg, int* __restrict__ block_sums)
{
    __shared__ int sdata[BLOCK];
    int i = blockIdx.x * BLOCK + threadIdx.x;
    sdata[threadIdx.x] = (i < N_NODES) ? deg[i] : 0;
    __syncthreads();
    for (int s = BLOCK / 2; s > 0; s >>= 1) {
        if (threadIdx.x < s) sdata[threadIdx.x] += sdata[threadIdx.x + s];
        __syncthreads();
    }
    if (threadIdx.x == 0) block_sums[blockIdx.x] = sdata[0];
}

__global__ __launch_bounds__(512) void scan_block_sums(int* __restrict__ block_sums)
{
    // single block, 512 threads >= N_SCAN_BLOCKS(391)
    __shared__ int sdata[512];
    int t = threadIdx.x;
    int v = (t < N_SCAN_BLOCKS) ? block_sums[t] : 0;
    sdata[t] = v;
    __syncthreads();
    for (int d = 1; d < 512; d <<= 1) {
        int add = (t >= d) ? sdata[t - d] : 0;
        __syncthreads();
        sdata[t] += add;
        __syncthreads();
    }
    if (t < N_SCAN_BLOCKS) block_sums[t] = sdata[t] - v;  // exclusive
}

__global__ __launch_bounds__(BLOCK) void scan_write_offsets(
    const int* __restrict__ deg, const int* __restrict__ block_sums,
    int* __restrict__ offsets, int* __restrict__ cursor)
{
    __shared__ int sdata[BLOCK];
    int i = blockIdx.x * BLOCK + threadIdx.x;
    int v = (i < N_NODES) ? deg[i] : 0;
    sdata[threadIdx.x] = v;
    __syncthreads();
    for (int d = 1; d < BLOCK; d <<= 1) {
        int add = (threadIdx.x >= d) ? sdata[threadIdx.x - d] : 0;
        __syncthreads();
        sdata[threadIdx.x] += add;
        __syncthreads();
    }
    int excl = sdata[threadIdx.x] - v + block_sums[blockIdx.x];
    if (i < N_NODES) { offsets[i] = excl; cursor[i] = excl; }
    if (i == N_NODES - 1) offsets[N_NODES] = excl + v;  // == N_EDGES
}

__global__ __launch_bounds__(BLOCK) void scatter_pairs(
    const int* __restrict__ src, const int* __restrict__ dst,
    const float* __restrict__ ew, const float* __restrict__ w_mp,
    int* __restrict__ cursor, int2* __restrict__ pairs)
{
    int e = blockIdx.x * BLOCK + threadIdx.x;
    if (e >= N_EDGES) return;
    float c = w_mp[0] * ew[e];
    int p = atomicAdd(&cursor[dst[e]], 1);
    int2 pr;
    pr.x = src[e];
    pr.y = __float_as_int(c);
    pairs[p] = pr;
}

__global__ __launch_bounds__(BLOCK) void gather_sum(
    const int* __restrict__ offsets, const int2* __restrict__ pairs,
    const float* __restrict__ x, float* __restrict__ out)
{
    int gid  = blockIdx.x * BLOCK + threadIdx.x;
    int node = gid >> 3;          // 8 threads per node
    int f4   = (gid & 7) * 4;     // float4 slice of the 32-float row
    if (node >= N_NODES) return;
    int off = offsets[node];
    int end = offsets[node + 1];
    float4 acc = make_float4(0.f, 0.f, 0.f, 0.f);
    for (int j = off; j < end; ++j) {
        int2 pr = pairs[j];
        float c = __int_as_float(pr.y);
        const float4 xv = *reinterpret_cast<const float4*>(
            x + (size_t)pr.x * F_DIM + f4);
        acc.x += c * xv.x;
        acc.y += c * xv.y;
        acc.z += c * xv.z;
        acc.w += c * xv.w;
    }
    *reinterpret_cast<float4*>(out + (size_t)node * F_DIM + f4) = acc;
}

// ---------------- fallback (R0): plain atomic scatter ----------------
__global__ __launch_bounds__(BLOCK) void gnn_scatter_atomic(
    const float* __restrict__ x, const int* __restrict__ src,
    const int* __restrict__ dst, const float* __restrict__ ew,
    const float* __restrict__ w_mp, float* __restrict__ out)
{
    const float w = w_mp[0];
    int gid = blockIdx.x * blockDim.x + threadIdx.x;
    int e = gid >> 3;
    int q = (gid & 7) * 4;
    if (e >= N_EDGES) return;
    int s = src[e];
    int d = dst[e];
    float c = w * ew[e];
    const float4 xv = *reinterpret_cast<const float4*>(x + (size_t)s * F_DIM + q);
    float* op = out + (size_t)d * F_DIM + q;
    atomicAdd(op + 0, c * xv.x);
    atomicAdd(op + 1, c * xv.y);
    atomicAdd(op + 2, c * xv.z);
    atomicAdd(op + 3, c * xv.w);
}

extern "C" void kernel_launch(void* const* d_in, const int* in_sizes, int n_in,
                              void* d_out, int out_size, void* d_ws, size_t ws_size,
                              hipStream_t stream) {
    const float* x    = (const float*)d_in[0];
    const int*   ei   = (const int*)d_in[1];   // [2, E]: src row, then dst row
    const float* ew   = (const float*)d_in[2];
    const float* w_mp = (const float*)d_in[3];
    float* out = (float*)d_out;

    const int* src = ei;
    const int* dst = ei + N_EDGES;

    if (ws_size < WS_NEEDED) {
        // fallback: R0 atomic path (ws too small for CSR build)
        hipMemsetAsync(d_out, 0, (size_t)out_size * sizeof(float), stream);
        int total = N_EDGES * 8;
        gnn_scatter_atomic<<<(total + BLOCK - 1) / BLOCK, BLOCK, 0, stream>>>(
            x, src, dst, ew, w_mp, out);
        return;
    }

    char* ws = (char*)d_ws;
    int*  deg     = (int*)(ws + WS_DEG);
    int*  offsets = (int*)(ws + WS_OFFS);
    int*  cursor  = (int*)(ws + WS_CURSOR);
    int*  bsums   = (int*)(ws + WS_BSUMS);
    int2* pairs   = (int2*)(ws + WS_PAIRS);

    hipMemsetAsync(deg, 0, (size_t)N_NODES * sizeof(int), stream);

    int eblocks = (N_EDGES + BLOCK - 1) / BLOCK;  // 6250
    hist_deg<<<eblocks, BLOCK, 0, stream>>>(dst, deg);

    block_reduce_deg<<<N_SCAN_BLOCKS, BLOCK, 0, stream>>>(deg, bsums);
    scan_block_sums<<<1, 512, 0, stream>>>(bsums);
    scan_write_offsets<<<N_SCAN_BLOCKS, BLOCK, 0, stream>>>(deg, bsums, offsets, cursor);

    scatter_pairs<<<eblocks, BLOCK, 0, stream>>>(src, dst, ew, w_mp, cursor, pairs);

    int gthreads = N_NODES * 8;
    gather_sum<<<(gthreads + BLOCK - 1) / BLOCK, BLOCK, 0, stream>>>(
        offsets, pairs, x, out);
}